// Round 1
// baseline (3807.941 us; speedup 1.0000x reference)
//
#include <hip/hip_runtime.h>
#include <cstdint>
#include <cstddef>

static constexpr int T_STEPS = 2048;
static constexpr int BATCH   = 32;
static constexpr int DIM     = 256;   // input dim == hidden dim
static constexpr int NCOL    = 512;   // pre columns actually used (h-gate, t-gate)
static constexpr size_t M_ROWS = (size_t)T_STEPS * BATCH;  // 65536

typedef _Float16 h2_t  __attribute__((ext_vector_type(2)));
typedef _Float16 f16x8 __attribute__((ext_vector_type(8)));
typedef float    f32x4 __attribute__((ext_vector_type(4)));

struct alignas(16) H8 { h2_t a, b, c, d; };
struct alignas(8)  H4 { _Float16 x, y, z, w; };

// ---- workspace layout (bytes) ----
// [0, 64MB)        XW f16 [65536][512]   (reused by both layers)
// [64MB, 96MB)     A  f16 [65536][256]   (inp_f16 for layer0 GEMM; then out0 for layer1 GEMM)
// [96MB, +256KB)   blob0 (Wih0 cols 0:512 in MFMA-B fragment layout)
// [...,  +256KB)   blob1
static constexpr size_t XW_OFF = 0;
static constexpr size_t A_OFF  = M_ROWS * NCOL * 2;            // 67108864
static constexpr size_t B0_OFF = A_OFF + M_ROWS * DIM * 2;     // +33554432
static constexpr size_t B1_OFF = B0_OFF + (size_t)DIM * NCOL * 2;

__device__ __forceinline__ float fdot2(h2_t a, h2_t b, float c) {
  return __builtin_amdgcn_fdot2(a, b, c, false);
}

// ---------------- prep: f32 -> f16 convert (input) ----------------
__global__ void cvt_f32_to_f16(const float* __restrict__ src, _Float16* __restrict__ dst, int n4) {
  int i = blockIdx.x * blockDim.x + threadIdx.x;
  if (i >= n4) return;
  float4 v = ((const float4*)src)[i];
  H4 o; o.x = (_Float16)v.x; o.y = (_Float16)v.y; o.z = (_Float16)v.z; o.w = (_Float16)v.w;
  ((H4*)dst)[i] = o;
}

// ---------------- prep: Wih -> MFMA B-fragment blob ----------------
// blob[nt][kc][lane][j] = B[kc*32 + (lane>>4)*8 + j][nt*16 + (lane&15)],  B = Wih[:, 0:512]
__global__ void prep_blobs(const float* __restrict__ wih0, const float* __restrict__ wih1,
                           _Float16* __restrict__ blob0, _Float16* __restrict__ blob1) {
  int gid = blockIdx.x * blockDim.x + threadIdx.x;   // < 2*256*512
  int mat = gid >> 17;
  int rem = gid & 131071;
  int k = rem >> 9;        // 0..255
  int n = rem & 511;       // 0..511
  float v = (mat ? wih1 : wih0)[k * 768 + n];
  int kc = k >> 5, q = (k >> 3) & 3, j = k & 7, nt = n >> 4;
  int lane = (n & 15) + 16 * q;
  _Float16* b = mat ? blob1 : blob0;
  b[((size_t)(nt * 8 + kc) * 64 + lane) * 8 + j] = (_Float16)v;
}

// ---------------- GEMM: XW = A[65536,256] @ B[256,512]  (f16 MFMA, f32 acc) ----------------
// Each wave: 16 m-rows x 256 n-cols strip. 16x16x32 MFMA; A-frag: A[m=lane&15][k=q*8+j];
// B-frag from pre-shuffled blob (coalesced dwordx4); C/D: col=lane&15, row=q*4+reg.
__global__ __launch_bounds__(256) void gemm_xw(const _Float16* __restrict__ A,
                                               const _Float16* __restrict__ blob,
                                               _Float16* __restrict__ XW) {
  int lane = threadIdx.x & 63;
  int wave = threadIdx.x >> 6;
  int wid  = blockIdx.x * 4 + wave;       // 0..8191
  int mbase = (wid >> 1) * 16;
  int nhalf = wid & 1;
  int q = lane >> 4, n15 = lane & 15;

  f32x4 acc[16];
#pragma unroll
  for (int i = 0; i < 16; i++) acc[i] = (f32x4){0.f, 0.f, 0.f, 0.f};

  const _Float16* Arow = A + (size_t)(mbase + n15) * DIM + q * 8;
#pragma unroll
  for (int kc = 0; kc < 8; kc++) {
    f16x8 af = *(const f16x8*)(Arow + kc * 32);
#pragma unroll
    for (int nt = 0; nt < 16; nt++) {
      const _Float16* bp = blob + ((size_t)((nhalf * 16 + nt) * 8 + kc) * 64 + lane) * 8;
      f16x8 bf = *(const f16x8*)bp;
      acc[nt] = __builtin_amdgcn_mfma_f32_16x16x32_f16(af, bf, acc[nt], 0, 0, 0);
    }
  }
#pragma unroll
  for (int nt = 0; nt < 16; nt++) {
#pragma unroll
    for (int r = 0; r < 4; r++) {
      int m   = mbase + q * 4 + r;
      int col = nhalf * 256 + nt * 16 + n15;
      XW[(size_t)m * NCOL + col] = (_Float16)acc[nt][r];
    }
  }
}

// ---------------- recurrence ----------------
__device__ __forceinline__ int read_len(const void* p, int b) {
  // length is int64 per the reference, but harness may hand us int32.
  // int64 interpretation is valid iff every value lands in [0, 2048].
  const long long* q = (const long long*)p;
  bool ok64 = true;
  for (int i = 0; i < 32; i++) { long long v = q[i]; if (v < 0 || v > 2048) ok64 = false; }
  return ok64 ? (int)q[b] : ((const int*)p)[b];
}

__device__ __forceinline__ float sigmoidf_(float x) { return 1.f / (1.f + __expf(-x)); }
__device__ __forceinline__ float tanhf_(float x) {
  float e = __expf(-2.f * fabsf(x));      // e in (0,1], never overflows
  float t = (1.f - e) / (1.f + e);
  return copysignf(t, x);
}

template <int LAYER>
__global__ __launch_bounds__(512, 2) void recur(const _Float16* __restrict__ xw,
                                                const float* __restrict__ whh,
                                                const float* __restrict__ bias,
                                                const void* __restrict__ lenp,
                                                _Float16* __restrict__ out0,
                                                float* __restrict__ out1,
                                                float* __restrict__ hn) {
  int b = blockIdx.x;
  int j = threadIdx.x;                    // column of pre this thread owns (0..511)
  int len = read_len(lenp, b);

  // Whh column j resident in registers as 128 packed f16 pairs (128 VGPRs).
  h2_t w[128];
#pragma unroll
  for (int kk = 0; kk < 128; kk++) {
    float w0 = whh[(size_t)(2 * kk) * 768 + j];
    float w1 = whh[(size_t)(2 * kk + 1) * 768 + j];
    h2_t p; p[0] = (_Float16)w0; p[1] = (_Float16)w1;
    w[kk] = p;
  }
  float bj = bias[j];

  __shared__ __align__(16) _Float16 hs[DIM];   // current h, f16 (GEMV broadcast source)
  __shared__ float pret[DIM];                  // t-gate pre-activations exchange
  if (j < DIM) hs[j] = (_Float16)0.f;
  float hown = 0.f;                            // f32 h for threads j<256
  __syncthreads();

  for (int t = 0; t < len; t++) {
    float xv = (float)xw[((size_t)t * BATCH + b) * NCOL + j];   // issued early, consumed late
    float a0 = 0.f, a1 = 0.f, a2 = 0.f, a3 = 0.f;
    const H8* hp = (const H8*)hs;
#pragma unroll
    for (int m = 0; m < 32; m++) {
      H8 hh = hp[m];                          // ds_read_b128, same-addr broadcast across lanes
      a0 = fdot2(hh.a, w[4 * m + 0], a0);
      a1 = fdot2(hh.b, w[4 * m + 1], a1);
      a2 = fdot2(hh.c, w[4 * m + 2], a2);
      a3 = fdot2(hh.d, w[4 * m + 3], a3);
    }
    float pre = (a0 + a1) + (a2 + a3) + xv + bj;
    if (j >= DIM) pret[j - DIM] = pre;
    __syncthreads();
    if (j < DIM) {
      float pt = pret[j];
      float tg = sigmoidf_(pt);
      float cg = sigmoidf_(tg);               // bug-faithful: sigmoid of sigmoid
      float s  = tanhf_(pre) * tg + hown * cg;
      hown = s;                               // t < len guaranteed: update unconditionally
      hs[j] = (_Float16)s;
      if (LAYER == 0)
        out0[((size_t)t * BATCH + b) * DIM + j] = (_Float16)s;
      else
        out1[((size_t)t * BATCH + b) * DIM + j] = s;
    }
    __syncthreads();
  }
  if (j < DIM) hn[LAYER * (BATCH * DIM) + b * DIM + j] = hown;
  if (LAYER == 1 && j < DIM) {
    for (int t = len; t < T_STEPS; t++)       // frozen region: out = frozen h
      out1[((size_t)t * BATCH + b) * DIM + j] = hown;
  }
}

extern "C" void kernel_launch(void* const* d_in, const int* in_sizes, int n_in,
                              void* d_out, int out_size, void* d_ws, size_t ws_size,
                              hipStream_t stream) {
  const float* input_ = (const float*)d_in[0];
  const void*  lenp   = d_in[1];
  const float* Wih0   = (const float*)d_in[2];
  const float* Whh0   = (const float*)d_in[3];
  const float* b0     = (const float*)d_in[4];
  const float* Wih1   = (const float*)d_in[5];
  const float* Whh1   = (const float*)d_in[6];
  const float* b1     = (const float*)d_in[7];
  float* out = (float*)d_out;
  char*  ws  = (char*)d_ws;

  _Float16* XW    = (_Float16*)(ws + XW_OFF);
  _Float16* Abuf  = (_Float16*)(ws + A_OFF);
  _Float16* blob0 = (_Float16*)(ws + B0_OFF);
  _Float16* blob1 = (_Float16*)(ws + B1_OFF);
  float* hn = out + M_ROWS * DIM;   // d_out tail: h_n [2][32][256]

  // 1. input f32 -> f16 (A for layer0 GEMM)
  cvt_f32_to_f16<<<16384, 256, 0, stream>>>(input_, Abuf, (int)(M_ROWS * DIM / 4));
  // 2. Wih0/Wih1 (cols 0:512) -> MFMA B-fragment blobs
  prep_blobs<<<1024, 256, 0, stream>>>(Wih0, Wih1, blob0, blob1);
  // 3. XW0 = input @ Wih0[:, :512]
  gemm_xw<<<2048, 256, 0, stream>>>(Abuf, blob0, XW);
  // 4. layer0 recurrence: writes out0 (f16, overlaying Abuf) + hn0
  recur<0><<<32, 512, 0, stream>>>(XW, Whh0, b0, lenp, Abuf, nullptr, hn);
  // 5. XW1 = out0 @ Wih1[:, :512]   (rows t>=len are garbage, never read by recur<1>)
  gemm_xw<<<2048, 256, 0, stream>>>(Abuf, blob1, XW);
  // 6. layer1 recurrence: writes out1 (f32, d_out) + fill of frozen region + hn1
  recur<1><<<32, 512, 0, stream>>>(XW, Whh1, b1, lenp, nullptr, out, hn);
}